// Round 1
// baseline (350.910 us; speedup 1.0000x reference)
//
#include <hip/hip_runtime.h>
#include <hip/hip_bf16.h>

// ---------------- common types / helpers ----------------
typedef __bf16 bf16x8 __attribute__((ext_vector_type(8)));
typedef float  f32x4  __attribute__((ext_vector_type(4)));

__device__ __forceinline__ unsigned short f2bf(float f){
  union { float f; unsigned int u; } v; v.f = f;
  unsigned int r = (v.u + 0x7FFFu + ((v.u >> 16) & 1u)) >> 16;
  return (unsigned short)r;
}

__device__ __forceinline__ void gload_lds16(const void* g, void* l){
  __builtin_amdgcn_global_load_lds(
      (const __attribute__((address_space(1))) unsigned int*)g,
      (__attribute__((address_space(3))) unsigned int*)l, 16, 0, 0);
}

#define MFMA16(a,b,c) __builtin_amdgcn_mfma_f32_16x16x32_bf16((a),(b),(c),0,0,0)

// ---------------- constants ----------------
// B=2, S=2048, D=1024, R=128, H=16, Dh=64, NC=64, SD=64, K_trunc=32

// ---------------- convert x -> bf16 ----------------
__global__ void k_conv_x(const float* __restrict__ x, unsigned short* __restrict__ o){
  int i = (blockIdx.x * 256 + threadIdx.x) * 4;
  float4 v = *reinterpret_cast<const float4*>(x + i);
  ushort4 r; r.x = f2bf(v.x); r.y = f2bf(v.y); r.z = f2bf(v.z); r.w = f2bf(v.w);
  *reinterpret_cast<ushort4*>(o + i) = r;
}

// ---------------- convert weights -> bf16 (B^T layouts) ----------------
// wqkv: [3072][128]  (rows: 0..1023 Wq, 1024..2047 Wk, 2048..3071 Wv; each row o = W*[o][0..127])
// wo  : [1024][1024] (= Wo as-is, [o][d])
// wrt : [128][1024]  (rows 0..63 = W_router rows, 64..127 zero pad)
__global__ void k_conv_w(const float* __restrict__ Wq, const float* __restrict__ Wk,
                         const float* __restrict__ Wv, const float* __restrict__ Wo,
                         const float* __restrict__ Wr,
                         unsigned short* __restrict__ wqkv, unsigned short* __restrict__ wo,
                         unsigned short* __restrict__ wrt){
  int j = (blockIdx.x * 256 + threadIdx.x) * 4;
  if (j < 393216){
    const float* s;
    if (j < 131072) s = Wq + j; else if (j < 262144) s = Wk + (j - 131072); else s = Wv + (j - 262144);
    float4 v = *reinterpret_cast<const float4*>(s);
    ushort4 r; r.x = f2bf(v.x); r.y = f2bf(v.y); r.z = f2bf(v.z); r.w = f2bf(v.w);
    *reinterpret_cast<ushort4*>(wqkv + j) = r;
  } else if (j < 1441792){
    int jj = j - 393216;
    float4 v = *reinterpret_cast<const float4*>(Wo + jj);
    ushort4 r; r.x = f2bf(v.x); r.y = f2bf(v.y); r.z = f2bf(v.z); r.w = f2bf(v.w);
    *reinterpret_cast<ushort4*>(wo + jj) = r;
  } else {
    int jj = j - 1441792;
    int n = jj >> 10, d = jj & 1023;
    ushort4 r;
    if (n < 64){
      float4 v = *reinterpret_cast<const float4*>(Wr + n * 1024 + d);
      r.x = f2bf(v.x); r.y = f2bf(v.y); r.z = f2bf(v.z); r.w = f2bf(v.w);
    } else { r.x = 0; r.y = 0; r.z = 0; r.w = 0; }
    *reinterpret_cast<ushort4*>(wrt + jj) = r;
  }
}

// ---------------- generic bf16 GEMM: C[M,N] = A[M,K] * Bt[N,K]^T ----------------
// 128x128 tile, BK=64, 4 waves, each wave 64x64 (4x4 frags of 16x16x32 MFMA).
template<int CBF16>
__global__ __launch_bounds__(256) void k_gemm(
    const unsigned short* __restrict__ A, const unsigned short* __restrict__ Bt,
    void* __restrict__ Cv, int M, int N, int K,
    long sA, long sB, long sC)
{
  __shared__ __align__(16) unsigned short Al[128 * 64];
  __shared__ __align__(16) unsigned short Bl[128 * 64];
  const int tid = threadIdx.x, wv = tid >> 6, lane = tid & 63;
  const int bm = blockIdx.y * 128, bn = blockIdx.x * 128, z = blockIdx.z;
  const unsigned short* Ab = A + (long)z * sA;
  const unsigned short* Bb = Bt + (long)z * sB;
  const f32x4 zero = {0.f, 0.f, 0.f, 0.f};
  f32x4 acc[4][4];
  #pragma unroll
  for (int i = 0; i < 4; ++i)
    #pragma unroll
    for (int j = 0; j < 4; ++j) acc[i][j] = zero;
  const int mo = (wv & 1) * 64, no = (wv >> 1) * 64;

  for (int k0 = 0; k0 < K; k0 += 64){
    __syncthreads();
    #pragma unroll
    for (int i = 0; i < 4; ++i){
      int rr = (wv * 4 + i) * 8 + (lane >> 3);
      gload_lds16(Ab + (long)(bm + rr) * K + k0 + (lane & 7) * 8, &Al[(wv * 4 + i) * 8 * 64]);
      gload_lds16(Bb + (long)(bn + rr) * K + k0 + (lane & 7) * 8, &Bl[(wv * 4 + i) * 8 * 64]);
    }
    __syncthreads();
    #pragma unroll
    for (int ks = 0; ks < 2; ++ks){
      bf16x8 af[4], bfr[4];
      #pragma unroll
      for (int mi = 0; mi < 4; ++mi)
        af[mi] = *reinterpret_cast<const bf16x8*>(&Al[(mo + mi * 16 + (lane & 15)) * 64 + ks * 32 + (lane >> 4) * 8]);
      #pragma unroll
      for (int ni = 0; ni < 4; ++ni)
        bfr[ni] = *reinterpret_cast<const bf16x8*>(&Bl[(no + ni * 16 + (lane & 15)) * 64 + ks * 32 + (lane >> 4) * 8]);
      #pragma unroll
      for (int mi = 0; mi < 4; ++mi)
        #pragma unroll
        for (int ni = 0; ni < 4; ++ni)
          acc[mi][ni] = MFMA16(af[mi], bfr[ni], acc[mi][ni]);
    }
  }

  #pragma unroll
  for (int mi = 0; mi < 4; ++mi)
    #pragma unroll
    for (int ni = 0; ni < 4; ++ni)
      #pragma unroll
      for (int r = 0; r < 4; ++r){
        int row = bm + mo + mi * 16 + (lane >> 4) * 4 + r;
        int col = bn + no + ni * 16 + (lane & 15);
        float v = acc[mi][ni][r];
        if (CBF16) ((unsigned short*)Cv)[(long)z * sC + (long)row * N + col] = f2bf(v);
        else       ((float*)Cv)[(long)z * sC + (long)row * N + col] = v;
      }
}

// ---------------- xB for last 32 rows per batch ----------------
__global__ void k_xbt(const float* __restrict__ x, const float* __restrict__ Bs,
                      float* __restrict__ xbt){
  int b = blockIdx.x >> 5, t = blockIdx.x & 31, lane = threadIdx.x;
  const float* xr = x + ((long)b * 2048 + (2048 - 32 + t)) * 1024;
  float acc = 0.f;
  for (int d = 0; d < 1024; d += 4){
    float4 xv = *reinterpret_cast<const float4*>(xr + d);
    acc += xv.x * Bs[(d    ) * 64 + lane];
    acc += xv.y * Bs[(d + 1) * 64 + lane];
    acc += xv.z * Bs[(d + 2) * 64 + lane];
    acc += xv.w * Bs[(d + 3) * 64 + lane];
  }
  xbt[(b * 32 + t) * 64 + lane] = acc;
}

// ---------------- truncated scan (32 steps) + h_proj ----------------
__global__ void k_scan(const float* __restrict__ xbt, const float* __restrict__ A,
                       const float* __restrict__ Wimp, float* __restrict__ hproj){
  int b = blockIdx.x, j = threadIdx.x;
  float Ac[64];
  #pragma unroll
  for (int i = 0; i < 64; ++i) Ac[i] = A[i * 64 + j];
  __shared__ float hs[64];
  hs[j] = xbt[(b * 32) * 64 + j];
  __syncthreads();
  for (int t = 1; t < 32; ++t){
    float acc = xbt[(b * 32 + t) * 64 + j];
    #pragma unroll
    for (int i = 0; i < 64; i += 4){
      float4 h4 = *reinterpret_cast<const float4*>(&hs[i]);
      acc += h4.x * Ac[i] + h4.y * Ac[i + 1] + h4.z * Ac[i + 2] + h4.w * Ac[i + 3];
    }
    __syncthreads();
    hs[j] = acc;
    __syncthreads();
  }
  for (int ii = 0; ii < 16; ++ii){
    int d = ii * 64 + j;
    const float* wr = Wimp + d * 64;
    float acc = 0.f;
    #pragma unroll
    for (int k = 0; k < 64; k += 4){
      float4 w4 = *reinterpret_cast<const float4*>(wr + k);
      float4 h4 = *reinterpret_cast<const float4*>(&hs[k]);
      acc += w4.x * h4.x + w4.y * h4.y + w4.z * h4.z + w4.w * h4.w;
    }
    hproj[b * 1024 + d] = acc;
  }
}

// ---------------- importance logits: l[b,s] = x[b,s,:] . hproj[b,:] (fp32) ----------------
__global__ void k_logits(const float* __restrict__ x, const float* __restrict__ hproj,
                         float* __restrict__ l){
  int tid = threadIdx.x, lane = tid & 63, wv = tid >> 6;
  int rowbase = blockIdx.x * 16;
  int b = rowbase >> 11;
  float hp[16];
  #pragma unroll
  for (int i = 0; i < 16; ++i) hp[i] = hproj[b * 1024 + i * 64 + lane];
  for (int rr = 0; rr < 4; ++rr){
    int row = rowbase + wv * 4 + rr;
    const float* xr = x + (long)row * 1024;
    float acc = 0.f;
    #pragma unroll
    for (int i = 0; i < 16; ++i) acc += xr[i * 64 + lane] * hp[i];
    #pragma unroll
    for (int o = 32; o; o >>= 1) acc += __shfl_xor(acc, o, 64);
    if (lane == 0) l[row] = acc;
  }
}

// ---------------- softmax over S per batch -> importance ----------------
__global__ void k_impsm(const float* __restrict__ l, float* __restrict__ imp){
  int b = blockIdx.x, tid = threadIdx.x, lane = tid & 63, wv = tid >> 6;
  __shared__ float red[16];
  float v0 = l[b * 2048 + tid], v1 = l[b * 2048 + 1024 + tid];
  float m = fmaxf(v0, v1);
  #pragma unroll
  for (int o = 32; o; o >>= 1) m = fmaxf(m, __shfl_xor(m, o, 64));
  if (lane == 0) red[wv] = m;
  __syncthreads();
  float M = red[0];
  #pragma unroll
  for (int i = 1; i < 16; ++i) M = fmaxf(M, red[i]);
  __syncthreads();
  float e0 = __expf(v0 - M), e1 = __expf(v1 - M);
  float s = e0 + e1;
  #pragma unroll
  for (int o = 32; o; o >>= 1) s += __shfl_xor(s, o, 64);
  if (lane == 0) red[wv] = s;
  __syncthreads();
  float S = 0.f;
  #pragma unroll
  for (int i = 0; i < 16; ++i) S += red[i];
  float inv = 1.f / S;
  imp[b * 2048 + tid] = e0 * inv;
  imp[b * 2048 + 1024 + tid] = e1 * inv;
}

// ---------------- nw partials: softmax over 64 router cols, weight by importance ----------------
__global__ void k_nwpart(const float* __restrict__ rp, const float* __restrict__ imp,
                         float* __restrict__ nwp){
  int bid = blockIdx.x; int b = bid >> 4, chunk = bid & 15;
  int tid = threadIdx.x, wv = tid >> 6, lane = tid & 63;
  float accn = 0.f;
  for (int t = 0; t < 32; ++t){
    int s = chunk * 128 + wv * 32 + t;
    float v = rp[((long)b * 2048 + s) * 128 + lane];
    float mx = v;
    #pragma unroll
    for (int o = 32; o; o >>= 1) mx = fmaxf(mx, __shfl_xor(mx, o, 64));
    float e = __expf(v - mx);
    float sm = e;
    #pragma unroll
    for (int o = 32; o; o >>= 1) sm += __shfl_xor(sm, o, 64);
    accn += imp[b * 2048 + s] * (e / sm);
  }
  __shared__ float red[4][64];
  red[wv][lane] = accn;
  __syncthreads();
  if (wv == 0){
    float t = red[0][lane] + red[1][lane] + red[2][lane] + red[3][lane];
    nwp[bid * 64 + lane] = t;
  }
}

__global__ void k_nwfin(const float* __restrict__ nwp, float* __restrict__ nw){
  int b = blockIdx.x, lane = threadIdx.x;
  float a = 0.f;
  #pragma unroll
  for (int c = 0; c < 16; ++c) a += nwp[(b * 16 + c) * 64 + lane];
  float tot = a;
  #pragma unroll
  for (int o = 32; o; o >>= 1) tot += __shfl_xor(tot, o, 64);
  nw[b * 64 + lane] = a / (tot + 1e-8f);
}

// ---------------- shared_compress^T: sct[b][r][d] = sum_n nw[b][n]*cn[n][d][r] (bf16 out) ----------------
__global__ void k_sc(const float* __restrict__ cn, const float* __restrict__ nw,
                     unsigned short* __restrict__ sct){
  int tid = threadIdx.x;
  long idx = (long)blockIdx.x * 256 + tid;
  int d = (int)(idx >> 5); int r0 = (int)(idx & 31) * 4;
  __shared__ float nws[128];
  if (tid < 128) nws[tid] = nw[tid];
  __syncthreads();
  f32x4 a0 = {0.f,0.f,0.f,0.f}, a1 = {0.f,0.f,0.f,0.f};
  for (int n = 0; n < 64; ++n){
    f32x4 c = *reinterpret_cast<const f32x4*>(&cn[((long)n * 1024 + d) * 128 + r0]);
    a0 += nws[n] * c;
    a1 += nws[64 + n] * c;
  }
  #pragma unroll
  for (int e = 0; e < 4; ++e){
    sct[(long)(r0 + e) * 1024 + d]        = f2bf(a0[e]);
    sct[(long)(128 + r0 + e) * 1024 + d]  = f2bf(a1[e]);
  }
}

// ---------------- flash attention (causal), bf16 MFMA ----------------
__global__ __launch_bounds__(256) void k_attn(const unsigned short* __restrict__ qkv,
                                              unsigned short* __restrict__ ao){
  __shared__ __align__(16) unsigned short Kl[64 * 64];
  __shared__ __align__(16) unsigned short Vt[64 * 64];
  __shared__ __align__(16) unsigned short Pl[4][16 * 64];
  const int tid = threadIdx.x, wv = tid >> 6, lane = tid & 63;
  const int qb = blockIdx.x, h = blockIdx.y, b = blockIdx.z;
  const unsigned short* base = qkv + (long)b * 2048 * 3072;
  const int qrow = qb * 64 + wv * 16 + (lane & 15);
  bf16x8 qf[2];
  #pragma unroll
  for (int ks = 0; ks < 2; ++ks)
    qf[ks] = *reinterpret_cast<const bf16x8*>(&base[(long)qrow * 3072 + h * 64 + ks * 32 + (lane >> 4) * 8]);
  const f32x4 zero = {0.f,0.f,0.f,0.f};
  f32x4 oacc[4]; float m_r[4], l_r[4];
  #pragma unroll
  for (int i = 0; i < 4; ++i){ oacc[i] = zero; m_r[i] = -1e30f; l_r[i] = 0.f; }
  char* pw = (char*)&Pl[wv][0];
  const int qg0 = qb * 64 + wv * 16 + (lane >> 4) * 4;

  for (int kt = 0; kt <= qb; ++kt){
    __syncthreads();
    {
      int key = tid & 63;
      const unsigned short* krow = base + (long)(kt * 64 + key) * 3072 + 1024 + h * 64;
      const unsigned short* vrow = krow + 1024;
      #pragma unroll
      for (int half = 0; half < 2; ++half){
        int dg = (tid >> 6) + half * 4;
        uint4 kv = *reinterpret_cast<const uint4*>(krow + dg * 8);
        *reinterpret_cast<uint4*>((char*)Kl + key * 128 + ((dg * 16) ^ ((key & 7) << 4))) = kv;
        uint4 vvv = *reinterpret_cast<const uint4*>(vrow + dg * 8);
        const unsigned short* vs = reinterpret_cast<const unsigned short*>(&vvv);
        #pragma unroll
        for (int e = 0; e < 8; ++e){
          int dh = dg * 8 + e;
          *reinterpret_cast<unsigned short*>((char*)Vt + dh * 128 + ((key * 2) ^ ((dh & 7) << 4))) = vs[e];
        }
      }
    }
    __syncthreads();

    f32x4 sacc[4];
    #pragma unroll
    for (int i = 0; i < 4; ++i) sacc[i] = zero;
    #pragma unroll
    for (int kt16 = 0; kt16 < 4; ++kt16){
      int krw = kt16 * 16 + (lane & 15);
      #pragma unroll
      for (int ks = 0; ks < 2; ++ks){
        bf16x8 kf = *reinterpret_cast<const bf16x8*>((char*)Kl + krw * 128 + ((ks * 64 + (lane >> 4) * 16) ^ ((krw & 7) << 4)));
        sacc[kt16] = MFMA16(qf[ks], kf, sacc[kt16]);
      }
    }

    #pragma unroll
    for (int r = 0; r < 4; ++r){
      int qg = qg0 + r;
      float pv[4]; float mx = -1e30f;
      #pragma unroll
      for (int kt16 = 0; kt16 < 4; ++kt16){
        float s = sacc[kt16][r] * 0.125f;
        int kg = kt * 64 + kt16 * 16 + (lane & 15);
        s = (kg > qg) ? -1e30f : s;
        pv[kt16] = s; mx = fmaxf(mx, s);
      }
      #pragma unroll
      for (int o = 1; o < 16; o <<= 1) mx = fmaxf(mx, __shfl_xor(mx, o, 64));
      float mnew = fmaxf(m_r[r], mx);
      float scl = __expf(m_r[r] - mnew);
      float rs = 0.f;
      #pragma unroll
      for (int kt16 = 0; kt16 < 4; ++kt16){ float e = __expf(pv[kt16] - mnew); pv[kt16] = e; rs += e; }
      #pragma unroll
      for (int o = 1; o < 16; o <<= 1) rs += __shfl_xor(rs, o, 64);
      l_r[r] = l_r[r] * scl + rs;
      m_r[r] = mnew;
      #pragma unroll
      for (int dt = 0; dt < 4; ++dt) oacc[dt][r] *= scl;
      int q = (lane >> 4) * 4 + r;
      #pragma unroll
      for (int kt16 = 0; kt16 < 4; ++kt16){
        int keyc = kt16 * 16 + (lane & 15);
        *reinterpret_cast<unsigned short*>(pw + q * 128 + ((keyc * 2) ^ ((q & 7) << 4))) = f2bf(pv[kt16]);
      }
    }
    __syncthreads();  // P visible across lanes (safe round-1 choice)

    #pragma unroll
    for (int ks = 0; ks < 2; ++ks){
      int q = lane & 15;
      bf16x8 pf = *reinterpret_cast<const bf16x8*>(pw + q * 128 + ((ks * 64 + (lane >> 4) * 16) ^ ((q & 7) << 4)));
      #pragma unroll
      for (int dt = 0; dt < 4; ++dt){
        int dh = dt * 16 + (lane & 15);
        bf16x8 vf = *reinterpret_cast<const bf16x8*>((char*)Vt + dh * 128 + ((ks * 64 + (lane >> 4) * 16) ^ ((dh & 7) << 4)));
        oacc[dt] = MFMA16(pf, vf, oacc[dt]);
      }
    }
  }

  #pragma unroll
  for (int r = 0; r < 4; ++r){
    float inv = 1.f / l_r[r];
    int s = qb * 64 + wv * 16 + (lane >> 4) * 4 + r;
    #pragma unroll
    for (int dt = 0; dt < 4; ++dt)
      ao[((long)b * 2048 + s) * 1024 + h * 64 + dt * 16 + (lane & 15)] = f2bf(oacc[dt][r] * inv);
  }
}

// ---------------- launch ----------------
extern "C" void kernel_launch(void* const* d_in, const int* in_sizes, int n_in,
                              void* d_out, int out_size, void* d_ws, size_t ws_size,
                              hipStream_t stream){
  (void)in_sizes; (void)n_in; (void)out_size; (void)ws_size;
  const float* x    = (const float*)d_in[0];
  const float* A    = (const float*)d_in[1];
  const float* Bs   = (const float*)d_in[2];
  const float* Wimp = (const float*)d_in[3];
  const float* Wr   = (const float*)d_in[4];
  const float* cn   = (const float*)d_in[5];
  const float* Wq   = (const float*)d_in[6];
  const float* Wk   = (const float*)d_in[7];
  const float* Wv   = (const float*)d_in[8];
  const float* Wo   = (const float*)d_in[9];
  float* out = (float*)d_out;
  char* ws = (char*)d_ws;

  unsigned short* xb16  = (unsigned short*)(ws + 0);          //  8,388,608 B
  unsigned short* wqkv  = (unsigned short*)(ws + 8388608);    //    786,432 B
  unsigned short* wo_t  = (unsigned short*)(ws + 9175040);    //  2,097,152 B
  unsigned short* wrt   = (unsigned short*)(ws + 11272192);   //    262,144 B
  float*          rp    = (float*)(ws + 11534336);            //  2,097,152 B
  float*          xbt   = (float*)(ws + 13631488);            //     16,384 B
  float*          hproj = (float*)(ws + 13647872);            //      8,192 B
  float*          lbuf  = (float*)(ws + 13656064);            //     16,384 B
  float*          imp   = (float*)(ws + 13672448);            //     16,384 B
  float*          nwp   = (float*)(ws + 13688832);            //      8,192 B
  float*          nw    = (float*)(ws + 13697024);            //      1,024 B
  unsigned short* sct   = (unsigned short*)(ws + 13698048);   //    524,288 B
  unsigned short* hcomp = (unsigned short*)(ws + 14222336);   //  1,048,576 B
  unsigned short* qkvb  = (unsigned short*)(ws + 15270912);   // 25,165,824 B
  unsigned short* aob   = (unsigned short*)(ws + 40436736);   //  8,388,608 B  (total ~46.6 MB)

  k_conv_x<<<4096, 256, 0, stream>>>(x, xb16);
  k_conv_w<<<1536, 256, 0, stream>>>(Wq, Wk, Wv, Wo, Wr, wqkv, wo_t, wrt);
  // router logits (bf16): rp[4096][128] fp32 (cols 64..127 are zero-pad garbage, unused)
  k_gemm<0><<<dim3(1, 32, 1), 256, 0, stream>>>(xb16, wrt, rp, 4096, 128, 1024, 0, 0, 0);
  k_xbt<<<64, 64, 0, stream>>>(x, Bs, xbt);
  k_scan<<<2, 64, 0, stream>>>(xbt, A, Wimp, hproj);
  k_logits<<<256, 256, 0, stream>>>(x, hproj, lbuf);
  k_impsm<<<2, 1024, 0, stream>>>(lbuf, imp);
  k_nwpart<<<32, 256, 0, stream>>>(rp, imp, nwp);
  k_nwfin<<<2, 64, 0, stream>>>(nwp, nw);
  k_sc<<<128, 256, 0, stream>>>(cn, nw, sct);
  // hcomp[b] = xb16[b] @ sct[b]^T : M=2048 N=128 K=1024
  k_gemm<1><<<dim3(1, 16, 2), 256, 0, stream>>>(xb16, sct, hcomp, 2048, 128, 1024,
                                                2048L * 1024, 128L * 1024, 2048L * 128);
  // qkv[b] = hcomp[b] @ wqkv^T : M=2048 N=3072 K=128
  k_gemm<1><<<dim3(24, 16, 2), 256, 0, stream>>>(hcomp, wqkv, qkvb, 2048, 3072, 128,
                                                 2048L * 128, 0, 2048L * 3072);
  k_attn<<<dim3(32, 16, 2), 256, 0, stream>>>(qkvb, aob);
  // out = aob @ wo^T : M=4096 N=1024 K=1024 (fp32 out)
  k_gemm<0><<<dim3(8, 32, 1), 256, 0, stream>>>(aob, wo_t, out, 4096, 1024, 1024, 0, 0, 0);
}

// Round 2
// 278.522 us; speedup vs baseline: 1.2599x; 1.2599x over previous
//
#include <hip/hip_runtime.h>
#include <hip/hip_bf16.h>

// ---------------- common types / helpers ----------------
typedef __bf16 bf16x8 __attribute__((ext_vector_type(8)));
typedef __bf16 bf16x2 __attribute__((ext_vector_type(2)));
typedef float  f32x4  __attribute__((ext_vector_type(4)));
typedef float  f32x16 __attribute__((ext_vector_type(16)));
typedef unsigned int uint4v __attribute__((ext_vector_type(4)));

__device__ __forceinline__ unsigned short f2bf(float f){
  union { float f; unsigned int u; } v; v.f = f;
  unsigned int r = (v.u + 0x7FFFu + ((v.u >> 16) & 1u)) >> 16;
  return (unsigned short)r;
}

__device__ __forceinline__ unsigned pkbf(float a, float b){
  unsigned r;
  asm("v_cvt_pk_bf16_f32 %0, %1, %2" : "=v"(r) : "v"(a), "v"(b));
  return r;
}

__device__ __forceinline__ void gload_lds16(const void* g, void* l){
  __builtin_amdgcn_global_load_lds(
      (const __attribute__((address_space(1))) unsigned int*)g,
      (__attribute__((address_space(3))) unsigned int*)l, 16, 0, 0);
}

#define MFMA16(a,b,c) __builtin_amdgcn_mfma_f32_16x16x32_bf16((a),(b),(c),0,0,0)
#define MFMA32(a,b,c) __builtin_amdgcn_mfma_f32_32x32x16_bf16((a),(b),(c),0,0,0)

// ---------------- constants ----------------
// B=2, S=2048, D=1024, R=128, H=16, Dh=64, NC=64, SD=64, K_trunc=32

// ---------------- convert x -> bf16 ----------------
__global__ void k_conv_x(const float* __restrict__ x, unsigned short* __restrict__ o){
  int i = (blockIdx.x * 256 + threadIdx.x) * 4;
  float4 v = *reinterpret_cast<const float4*>(x + i);
  ushort4 r; r.x = f2bf(v.x); r.y = f2bf(v.y); r.z = f2bf(v.z); r.w = f2bf(v.w);
  *reinterpret_cast<ushort4*>(o + i) = r;
}

// ---------------- convert weights -> bf16 (B^T layouts) ----------------
__global__ void k_conv_w(const float* __restrict__ Wq, const float* __restrict__ Wk,
                         const float* __restrict__ Wv, const float* __restrict__ Wo,
                         const float* __restrict__ Wr,
                         unsigned short* __restrict__ wqkv, unsigned short* __restrict__ wo,
                         unsigned short* __restrict__ wrt){
  int j = (blockIdx.x * 256 + threadIdx.x) * 4;
  if (j < 393216){
    const float* s;
    if (j < 131072) s = Wq + j; else if (j < 262144) s = Wk + (j - 131072); else s = Wv + (j - 262144);
    float4 v = *reinterpret_cast<const float4*>(s);
    ushort4 r; r.x = f2bf(v.x); r.y = f2bf(v.y); r.z = f2bf(v.z); r.w = f2bf(v.w);
    *reinterpret_cast<ushort4*>(wqkv + j) = r;
  } else if (j < 1441792){
    int jj = j - 393216;
    float4 v = *reinterpret_cast<const float4*>(Wo + jj);
    ushort4 r; r.x = f2bf(v.x); r.y = f2bf(v.y); r.z = f2bf(v.z); r.w = f2bf(v.w);
    *reinterpret_cast<ushort4*>(wo + jj) = r;
  } else {
    int jj = j - 1441792;
    int n = jj >> 10, d = jj & 1023;
    ushort4 r;
    if (n < 64){
      float4 v = *reinterpret_cast<const float4*>(Wr + n * 1024 + d);
      r.x = f2bf(v.x); r.y = f2bf(v.y); r.z = f2bf(v.z); r.w = f2bf(v.w);
    } else { r.x = 0; r.y = 0; r.z = 0; r.w = 0; }
    *reinterpret_cast<ushort4*>(wrt + jj) = r;
  }
}

// ---------------- generic bf16 GEMM: C[M,N] = A[M,K] * Bt[N,K]^T ----------------
template<int CBF16>
__global__ __launch_bounds__(256) void k_gemm(
    const unsigned short* __restrict__ A, const unsigned short* __restrict__ Bt,
    void* __restrict__ Cv, int M, int N, int K,
    long sA, long sB, long sC)
{
  __shared__ __align__(16) unsigned short Al[128 * 64];
  __shared__ __align__(16) unsigned short Bl[128 * 64];
  const int tid = threadIdx.x, wv = tid >> 6, lane = tid & 63;
  const int bm = blockIdx.y * 128, bn = blockIdx.x * 128, z = blockIdx.z;
  const unsigned short* Ab = A + (long)z * sA;
  const unsigned short* Bb = Bt + (long)z * sB;
  const f32x4 zero = {0.f, 0.f, 0.f, 0.f};
  f32x4 acc[4][4];
  #pragma unroll
  for (int i = 0; i < 4; ++i)
    #pragma unroll
    for (int j = 0; j < 4; ++j) acc[i][j] = zero;
  const int mo = (wv & 1) * 64, no = (wv >> 1) * 64;

  for (int k0 = 0; k0 < K; k0 += 64){
    __syncthreads();
    #pragma unroll
    for (int i = 0; i < 4; ++i){
      int rr = (wv * 4 + i) * 8 + (lane >> 3);
      gload_lds16(Ab + (long)(bm + rr) * K + k0 + (lane & 7) * 8, &Al[(wv * 4 + i) * 8 * 64]);
      gload_lds16(Bb + (long)(bn + rr) * K + k0 + (lane & 7) * 8, &Bl[(wv * 4 + i) * 8 * 64]);
    }
    __syncthreads();
    #pragma unroll
    for (int ks = 0; ks < 2; ++ks){
      bf16x8 af[4], bfr[4];
      #pragma unroll
      for (int mi = 0; mi < 4; ++mi)
        af[mi] = *reinterpret_cast<const bf16x8*>(&Al[(mo + mi * 16 + (lane & 15)) * 64 + ks * 32 + (lane >> 4) * 8]);
      #pragma unroll
      for (int ni = 0; ni < 4; ++ni)
        bfr[ni] = *reinterpret_cast<const bf16x8*>(&Bl[(no + ni * 16 + (lane & 15)) * 64 + ks * 32 + (lane >> 4) * 8]);
      #pragma unroll
      for (int mi = 0; mi < 4; ++mi)
        #pragma unroll
        for (int ni = 0; ni < 4; ++ni)
          acc[mi][ni] = MFMA16(af[mi], bfr[ni], acc[mi][ni]);
    }
  }

  #pragma unroll
  for (int mi = 0; mi < 4; ++mi)
    #pragma unroll
    for (int ni = 0; ni < 4; ++ni)
      #pragma unroll
      for (int r = 0; r < 4; ++r){
        int row = bm + mo + mi * 16 + (lane >> 4) * 4 + r;
        int col = bn + no + ni * 16 + (lane & 15);
        float v = acc[mi][ni][r];
        if (CBF16) ((unsigned short*)Cv)[(long)z * sC + (long)row * N + col] = f2bf(v);
        else       ((float*)Cv)[(long)z * sC + (long)row * N + col] = v;
      }
}

// ---------------- xB for last 32 rows per batch ----------------
__global__ void k_xbt(const float* __restrict__ x, const float* __restrict__ Bs,
                      float* __restrict__ xbt){
  int b = blockIdx.x >> 5, t = blockIdx.x & 31, lane = threadIdx.x;
  const float* xr = x + ((long)b * 2048 + (2048 - 32 + t)) * 1024;
  float acc = 0.f;
  for (int d = 0; d < 1024; d += 4){
    float4 xv = *reinterpret_cast<const float4*>(xr + d);
    acc += xv.x * Bs[(d    ) * 64 + lane];
    acc += xv.y * Bs[(d + 1) * 64 + lane];
    acc += xv.z * Bs[(d + 2) * 64 + lane];
    acc += xv.w * Bs[(d + 3) * 64 + lane];
  }
  xbt[(b * 32 + t) * 64 + lane] = acc;
}

// ---------------- truncated scan (32 steps) + h_proj ----------------
__global__ void k_scan(const float* __restrict__ xbt, const float* __restrict__ A,
                       const float* __restrict__ Wimp, float* __restrict__ hproj){
  int b = blockIdx.x, j = threadIdx.x;
  float Ac[64];
  #pragma unroll
  for (int i = 0; i < 64; ++i) Ac[i] = A[i * 64 + j];
  __shared__ float hs[64];
  hs[j] = xbt[(b * 32) * 64 + j];
  __syncthreads();
  for (int t = 1; t < 32; ++t){
    float acc = xbt[(b * 32 + t) * 64 + j];
    #pragma unroll
    for (int i = 0; i < 64; i += 4){
      float4 h4 = *reinterpret_cast<const float4*>(&hs[i]);
      acc += h4.x * Ac[i] + h4.y * Ac[i + 1] + h4.z * Ac[i + 2] + h4.w * Ac[i + 3];
    }
    __syncthreads();
    hs[j] = acc;
    __syncthreads();
  }
  for (int ii = 0; ii < 16; ++ii){
    int d = ii * 64 + j;
    const float* wr = Wimp + d * 64;
    float acc = 0.f;
    #pragma unroll
    for (int k = 0; k < 64; k += 4){
      float4 w4 = *reinterpret_cast<const float4*>(wr + k);
      float4 h4 = *reinterpret_cast<const float4*>(&hs[k]);
      acc += w4.x * h4.x + w4.y * h4.y + w4.z * h4.z + w4.w * h4.w;
    }
    hproj[b * 1024 + d] = acc;
  }
}

// ---------------- importance logits ----------------
__global__ void k_logits(const float* __restrict__ x, const float* __restrict__ hproj,
                         float* __restrict__ l){
  int tid = threadIdx.x, lane = tid & 63, wv = tid >> 6;
  int rowbase = blockIdx.x * 16;
  int b = rowbase >> 11;
  float hp[16];
  #pragma unroll
  for (int i = 0; i < 16; ++i) hp[i] = hproj[b * 1024 + i * 64 + lane];
  for (int rr = 0; rr < 4; ++rr){
    int row = rowbase + wv * 4 + rr;
    const float* xr = x + (long)row * 1024;
    float acc = 0.f;
    #pragma unroll
    for (int i = 0; i < 16; ++i) acc += xr[i * 64 + lane] * hp[i];
    #pragma unroll
    for (int o = 32; o; o >>= 1) acc += __shfl_xor(acc, o, 64);
    if (lane == 0) l[row] = acc;
  }
}

// ---------------- softmax over S per batch -> importance ----------------
__global__ void k_impsm(const float* __restrict__ l, float* __restrict__ imp){
  int b = blockIdx.x, tid = threadIdx.x, lane = tid & 63, wv = tid >> 6;
  __shared__ float red[16];
  float v0 = l[b * 2048 + tid], v1 = l[b * 2048 + 1024 + tid];
  float m = fmaxf(v0, v1);
  #pragma unroll
  for (int o = 32; o; o >>= 1) m = fmaxf(m, __shfl_xor(m, o, 64));
  if (lane == 0) red[wv] = m;
  __syncthreads();
  float M = red[0];
  #pragma unroll
  for (int i = 1; i < 16; ++i) M = fmaxf(M, red[i]);
  __syncthreads();
  float e0 = __expf(v0 - M), e1 = __expf(v1 - M);
  float s = e0 + e1;
  #pragma unroll
  for (int o = 32; o; o >>= 1) s += __shfl_xor(s, o, 64);
  if (lane == 0) red[wv] = s;
  __syncthreads();
  float S = 0.f;
  #pragma unroll
  for (int i = 0; i < 16; ++i) S += red[i];
  float inv = 1.f / S;
  imp[b * 2048 + tid] = e0 * inv;
  imp[b * 2048 + 1024 + tid] = e1 * inv;
}

// ---------------- nw partials ----------------
__global__ void k_nwpart(const float* __restrict__ rp, const float* __restrict__ imp,
                         float* __restrict__ nwp){
  int bid = blockIdx.x; int b = bid >> 4, chunk = bid & 15;
  int tid = threadIdx.x, wv = tid >> 6, lane = tid & 63;
  float accn = 0.f;
  for (int t = 0; t < 32; ++t){
    int s = chunk * 128 + wv * 32 + t;
    float v = rp[((long)b * 2048 + s) * 128 + lane];
    float mx = v;
    #pragma unroll
    for (int o = 32; o; o >>= 1) mx = fmaxf(mx, __shfl_xor(mx, o, 64));
    float e = __expf(v - mx);
    float sm = e;
    #pragma unroll
    for (int o = 32; o; o >>= 1) sm += __shfl_xor(sm, o, 64);
    accn += imp[b * 2048 + s] * (e / sm);
  }
  __shared__ float red[4][64];
  red[wv][lane] = accn;
  __syncthreads();
  if (wv == 0){
    float t = red[0][lane] + red[1][lane] + red[2][lane] + red[3][lane];
    nwp[bid * 64 + lane] = t;
  }
}

__global__ void k_nwfin(const float* __restrict__ nwp, float* __restrict__ nw){
  int b = blockIdx.x, lane = threadIdx.x;
  float a = 0.f;
  #pragma unroll
  for (int c = 0; c < 16; ++c) a += nwp[(b * 16 + c) * 64 + lane];
  float tot = a;
  #pragma unroll
  for (int o = 32; o; o >>= 1) tot += __shfl_xor(tot, o, 64);
  nw[b * 64 + lane] = a / (tot + 1e-8f);
}

// ---------------- shared_compress^T ----------------
__global__ void k_sc(const float* __restrict__ cn, const float* __restrict__ nw,
                     unsigned short* __restrict__ sct){
  int tid = threadIdx.x;
  long idx = (long)blockIdx.x * 256 + tid;
  int d = (int)(idx >> 5); int r0 = (int)(idx & 31) * 4;
  __shared__ float nws[128];
  if (tid < 128) nws[tid] = nw[tid];
  __syncthreads();
  f32x4 a0 = {0.f,0.f,0.f,0.f}, a1 = {0.f,0.f,0.f,0.f};
  for (int n = 0; n < 64; ++n){
    f32x4 c = *reinterpret_cast<const f32x4*>(&cn[((long)n * 1024 + d) * 128 + r0]);
    a0 += nws[n] * c;
    a1 += nws[64 + n] * c;
  }
  #pragma unroll
  for (int e = 0; e < 4; ++e){
    sct[(long)(r0 + e) * 1024 + d]        = f2bf(a0[e]);
    sct[(long)(128 + r0 + e) * 1024 + d]  = f2bf(a1[e]);
  }
}

// ---------------- flash attention v2: swapped-QK 32x32, paired q-blocks ----------------
// grid: 256 blocks x 512 thr. Block decode groups 8 pair-blocks of one (b,h) on one XCD.
// Waves 0-3: q-block 15-p, waves 4-7: q-block p  (each wave: 32 q rows).
// Per kv-tile (64 keys): S^T = mfma32(K, Q) -> lane-local q; in-register softmax;
// O^T = mfma32(V^T, P) so rescale stays lane-local.
__global__ __launch_bounds__(512, 2) void k_attn(const unsigned short* __restrict__ qkv,
                                                 unsigned short* __restrict__ ao){
  __shared__ __align__(16) unsigned short Kl[64 * 64];
  __shared__ __align__(16) unsigned short Vt[64 * 64];
  const int tid = threadIdx.x, wv = tid >> 6, lane = tid & 63;
  const int l31 = lane & 31, hi = lane >> 5;
  const float CEXP = 0.18033688011112042f;  // 0.125 * log2(e)

  // block decode with XCD grouping: XCD j (=li&7) hosts the 8 pair-blocks of group g
  int li = blockIdx.x;
  int j = li & 7, m = li >> 3;
  int g = j * 4 + (m & 3);     // 0..31 = (b,h)
  int p = m >> 2;              // pair index 0..7
  int h = g & 15, b = g >> 4;

  int qblock = (wv < 4) ? (15 - p) : p;
  int qbase = qblock * 128 + (wv & 3) * 32;
  int KTw = qbase >> 6;                 // last kv-tile this wave needs (masked)
  int ktmax = 2 * (15 - p) + 1;         // last kv-tile the block stages

  const unsigned short* base = qkv + (long)b * 2048 * 3072;

  // Q fragments: lane holds q-row qbase+l31, dh = 16*i + 8*hi + (0..7)
  bf16x8 qf[4];
  #pragma unroll
  for (int i = 0; i < 4; ++i)
    qf[i] = *reinterpret_cast<const bf16x8*>(base + (long)(qbase + l31) * 3072 + h * 64 + i * 16 + hi * 8);

  f32x16 oacc[2];
  #pragma unroll
  for (int d = 0; d < 2; ++d)
    #pragma unroll
    for (int r = 0; r < 16; ++r) oacc[d][r] = 0.f;
  float m_r = -3.0e38f, l_r = 0.f;

  for (int kt = 0; kt <= ktmax; ++kt){
    // ---- stage K (gload_lds, swizzled source) + V^T (scalar transpose writes) ----
    {
      int key = tid >> 3, c = tid & 7;
      int sc = c ^ (key & 7);
      gload_lds16(base + (long)(kt * 64 + key) * 3072 + 1024 + h * 64 + sc * 8,
                  (unsigned short*)Kl + wv * 512);
      int vk = lane;  // key row for V
      uint4 vvv = *reinterpret_cast<const uint4*>(base + (long)(kt * 64 + vk) * 3072 + 2048 + h * 64 + wv * 8);
      const unsigned short* vs = reinterpret_cast<const unsigned short*>(&vvv);
      #pragma unroll
      for (int e = 0; e < 8; ++e){
        int dh = wv * 8 + e;
        *reinterpret_cast<unsigned short*>((char*)Vt + dh * 128 + ((((vk >> 3) ^ (dh & 7))) << 4) + (vk & 7) * 2) = vs[e];
      }
    }
    __syncthreads();

    if (kt <= KTw){
      // ---- QK^T (swapped): S^T[key][q] ----
      f32x16 sa[2];
      #pragma unroll
      for (int kb = 0; kb < 2; ++kb){
        #pragma unroll
        for (int r = 0; r < 16; ++r) sa[kb][r] = 0.f;
        int row = kb * 32 + l31;
        #pragma unroll
        for (int i = 0; i < 4; ++i){
          bf16x8 kf = *reinterpret_cast<const bf16x8*>(
              (char*)Kl + row * 128 + ((((i << 1) | hi) ^ (l31 & 7)) << 4));
          sa[kb] = MFMA32(kf, qf[i], sa[kb]);
        }
      }

      // ---- softmax (lane-local q) ----
      float pv[32];
      #pragma unroll
      for (int kb = 0; kb < 2; ++kb)
        #pragma unroll
        for (int r = 0; r < 16; ++r) pv[kb * 16 + r] = sa[kb][r];

      if (kt == KTw){
        int qg = qbase + l31;
        #pragma unroll
        for (int kb = 0; kb < 2; ++kb)
          #pragma unroll
          for (int r = 0; r < 16; ++r){
            int kg = kt * 64 + kb * 32 + (r & 3) + ((r >> 2) << 3) + (hi << 2);
            if (kg > qg) pv[kb * 16 + r] = -3.0e38f;
          }
      }

      float mx = pv[0];
      #pragma unroll
      for (int r = 1; r < 32; ++r) mx = fmaxf(mx, pv[r]);
      mx = fmaxf(mx, __shfl_xor(mx, 32, 64));
      float mnew = fmaxf(m_r, mx);
      float scl = exp2f((m_r - mnew) * CEXP);
      float mn_c = mnew * CEXP;
      float rs = 0.f;
      #pragma unroll
      for (int r = 0; r < 32; ++r){
        float e = exp2f(__builtin_fmaf(pv[r], CEXP, -mn_c));
        pv[r] = e; rs += e;
      }
      rs += __shfl_xor(rs, 32, 64);
      l_r = l_r * scl + rs;
      m_r = mnew;
      #pragma unroll
      for (int d = 0; d < 2; ++d)
        #pragma unroll
        for (int r = 0; r < 16; ++r) oacc[d][r] *= scl;

      // ---- pack P to bf16 A-row fragments (cvt_pk + cross-half shfl) ----
      bf16x8 pa[4];
      #pragma unroll
      for (int kb = 0; kb < 2; ++kb){
        unsigned W[4][2], X[4][2];
        #pragma unroll
        for (int u = 0; u < 4; ++u){
          W[u][0] = pkbf(pv[kb * 16 + 4 * u + 0], pv[kb * 16 + 4 * u + 1]);
          W[u][1] = pkbf(pv[kb * 16 + 4 * u + 2], pv[kb * 16 + 4 * u + 3]);
        }
        #pragma unroll
        for (int u = 0; u < 4; ++u){
          X[u][0] = (unsigned)__shfl_xor((int)W[u][0], 32, 64);
          X[u][1] = (unsigned)__shfl_xor((int)W[u][1], 32, 64);
        }
        #pragma unroll
        for (int t2 = 0; t2 < 2; ++t2){
          int u0 = 2 * t2, u1 = u0 + 1;
          uint4v wt;
          wt.x = hi ? X[u1][0] : W[u0][0];
          wt.y = hi ? X[u1][1] : W[u0][1];
          wt.z = hi ? W[u1][0] : X[u0][0];
          wt.w = hi ? W[u1][1] : X[u0][1];
          pa[kb * 2 + t2] = __builtin_bit_cast(bf16x8, wt);
        }
      }

      // ---- PV: O^T[dh][q] += V^T · P^T ----
      #pragma unroll
      for (int db = 0; db < 2; ++db){
        int row = db * 32 + l31;
        #pragma unroll
        for (int t = 0; t < 4; ++t){
          bf16x8 vf = *reinterpret_cast<const bf16x8*>(
              (char*)Vt + row * 128 + ((((t << 1) | hi) ^ (l31 & 7)) << 4));
          oacc[db] = MFMA32(vf, pa[t], oacc[db]);
        }
      }
    }
    __syncthreads();
  }

  // ---- epilogue: O^T frag -> ao[b][q][h*64+dh] ----
  float inv = 1.f / l_r;
  int q = qbase + l31;
  unsigned short* aor = ao + ((long)b * 2048 + q) * 1024 + h * 64;
  #pragma unroll
  for (int db = 0; db < 2; ++db)
    #pragma unroll
    for (int r4 = 0; r4 < 4; ++r4){
      ushort4 o;
      o.x = f2bf(oacc[db][r4 * 4 + 0] * inv);
      o.y = f2bf(oacc[db][r4 * 4 + 1] * inv);
      o.z = f2bf(oacc[db][r4 * 4 + 2] * inv);
      o.w = f2bf(oacc[db][r4 * 4 + 3] * inv);
      int dh = db * 32 + r4 * 8 + hi * 4;
      *reinterpret_cast<ushort4*>(aor + dh) = o;
    }
}

// ---------------- launch ----------------
extern "C" void kernel_launch(void* const* d_in, const int* in_sizes, int n_in,
                              void* d_out, int out_size, void* d_ws, size_t ws_size,
                              hipStream_t stream){
  (void)in_sizes; (void)n_in; (void)out_size; (void)ws_size;
  const float* x    = (const float*)d_in[0];
  const float* A    = (const float*)d_in[1];
  const float* Bs   = (const float*)d_in[2];
  const float* Wimp = (const float*)d_in[3];
  const float* Wr   = (const float*)d_in[4];
  const float* cn   = (const float*)d_in[5];
  const float* Wq   = (const float*)d_in[6];
  const float* Wk   = (const float*)d_in[7];
  const float* Wv   = (const float*)d_in[8];
  const float* Wo   = (const float*)d_in[9];
  float* out = (float*)d_out;
  char* ws = (char*)d_ws;

  unsigned short* xb16  = (unsigned short*)(ws + 0);
  unsigned short* wqkv  = (unsigned short*)(ws + 8388608);
  unsigned short* wo_t  = (unsigned short*)(ws + 9175040);
  unsigned short* wrt   = (unsigned short*)(ws + 11272192);
  float*          rp    = (float*)(ws + 11534336);
  float*          xbt   = (float*)(ws + 13631488);
  float*          hproj = (float*)(ws + 13647872);
  float*          lbuf  = (float*)(ws + 13656064);
  float*          imp   = (float*)(ws + 13672448);
  float*          nwp   = (float*)(ws + 13688832);
  float*          nw    = (float*)(ws + 13697024);
  unsigned short* sct   = (unsigned short*)(ws + 13698048);
  unsigned short* hcomp = (unsigned short*)(ws + 14222336);
  unsigned short* qkvb  = (unsigned short*)(ws + 15270912);
  unsigned short* aob   = (unsigned short*)(ws + 40436736);

  k_conv_x<<<4096, 256, 0, stream>>>(x, xb16);
  k_conv_w<<<1536, 256, 0, stream>>>(Wq, Wk, Wv, Wo, Wr, wqkv, wo_t, wrt);
  k_gemm<0><<<dim3(1, 32, 1), 256, 0, stream>>>(xb16, wrt, rp, 4096, 128, 1024, 0, 0, 0);
  k_xbt<<<64, 64, 0, stream>>>(x, Bs, xbt);
  k_scan<<<2, 64, 0, stream>>>(xbt, A, Wimp, hproj);
  k_logits<<<256, 256, 0, stream>>>(x, hproj, lbuf);
  k_impsm<<<2, 1024, 0, stream>>>(lbuf, imp);
  k_nwpart<<<32, 256, 0, stream>>>(rp, imp, nwp);
  k_nwfin<<<2, 64, 0, stream>>>(nwp, nw);
  k_sc<<<128, 256, 0, stream>>>(cn, nw, sct);
  k_gemm<1><<<dim3(1, 16, 2), 256, 0, stream>>>(xb16, sct, hcomp, 2048, 128, 1024,
                                                2048L * 1024, 128L * 1024, 2048L * 128);
  k_gemm<1><<<dim3(24, 16, 2), 256, 0, stream>>>(hcomp, wqkv, qkvb, 2048, 3072, 128,
                                                 2048L * 128, 0, 2048L * 3072);
  k_attn<<<dim3(256), 512, 0, stream>>>(qkvb, aob);
  k_gemm<0><<<dim3(8, 32, 1), 256, 0, stream>>>(aob, wo_t, out, 4096, 1024, 1024, 0, 0, 0);
}